// Round 1
// 279.360 us; speedup vs baseline: 1.1375x; 1.1375x over previous
//
#include <hip/hip_runtime.h>
#include <hip/hip_fp16.h>

#define NU 50000
#define NM 50000
#define NN 100000
#define FU 32
#define FM 64
#define HD 128
#define NC 10

#define NB 196      // buckets of 256 destination cols
#define CAP 8192    // per-bucket staging capacity (mean 5102, +43 sigma)
#define CHUNK 4096  // edges per k_bucket block

typedef __attribute__((ext_vector_type(8))) _Float16 half8;
typedef __attribute__((ext_vector_type(4))) float f32x4;

// ============ scan helpers ============

__device__ inline int wave_incl_scan(int x, int l) {
#pragma unroll
    for (int d = 1; d < 64; d <<= 1) {
        int u = __shfl_up(x, d, 64);
        if (l >= d) x += u;
    }
    return x;
}

template <int NWAVE>
__device__ inline int block_excl_scan(int v, int t, int* wsum, int* out_total) {
    int l = t & 63, w = t >> 6;
    int inc = wave_incl_scan(v, l);
    if (l == 63) wsum[w] = inc;
    __syncthreads();
    int base = 0;
    int tot = 0;
#pragma unroll
    for (int i = 0; i < NWAVE; i++) {
        int s = wsum[i];
        if (i < w) base += s;
        tot += s;
    }
    if (out_total) *out_total = tot;
    return base + inc - v;
}

// ============ bucketed CSR build ============
// pairs[b*CAP + i] = row | (col<<16), grouped by bucket b = col>>8

__global__ void k_bucket(const int* __restrict__ row, const int* __restrict__ col, int E,
                         int* __restrict__ bucket_cur, unsigned int* __restrict__ pairs) {
    __shared__ int hist[NB];
    __shared__ int lofs[NB];
    __shared__ int gbase[NB];
    __shared__ int lcur[NB];
    __shared__ int wsum[4];
    __shared__ unsigned int stage[CHUNK];
    int t = threadIdx.x;
    int e0 = blockIdx.x * CHUNK;
    int cnt = min(CHUNK, E - e0);
    for (int i = t; i < NB; i += 256) hist[i] = 0;
    __syncthreads();
    unsigned int pk[CHUNK / 256];
#pragma unroll
    for (int i = 0; i < CHUNK / 256; i++) {
        int k = i * 256 + t;
        if (k < cnt) {
            unsigned int r = (unsigned int)row[e0 + k];
            unsigned int c = (unsigned int)col[e0 + k];
            pk[i] = r | (c << 16);
            atomicAdd(&hist[c >> 8], 1);
        }
    }
    __syncthreads();
    int v = (t < NB) ? hist[t] : 0;
    int excl = block_excl_scan<4>(v, t, wsum, nullptr);
    if (t < NB) {
        lofs[t] = excl;
        lcur[t] = excl;
        gbase[t] = atomicAdd(&bucket_cur[t], v);
    }
    __syncthreads();
#pragma unroll
    for (int i = 0; i < CHUNK / 256; i++) {
        int k = i * 256 + t;
        if (k < cnt) {
            int pos = atomicAdd(&lcur[pk[i] >> 24], 1);  // (c>>8) == pk>>24
            stage[pos] = pk[i];
        }
    }
    __syncthreads();
    int w = t >> 6, l = t & 63;
    for (int b = w; b < NB; b += 4) {
        int start = lofs[b], n = hist[b];
        unsigned int g = (unsigned int)b * CAP + (unsigned int)gbase[b];
        for (int i = l; i < n; i += 64) pairs[g + i] = stage[start + i];
    }
}

// per-col degree counts from bucketed pairs (one block per bucket)
__global__ void k_bcount(const unsigned int* __restrict__ pairs,
                         const int* __restrict__ bucket_cur, int* __restrict__ counts) {
    __shared__ int lc[256];
    int b = blockIdx.x, t = threadIdx.x;
    lc[t] = 0;
    __syncthreads();
    int n = bucket_cur[b];
    unsigned int base = (unsigned int)b * CAP;
    for (int i = t; i < n; i += 256) {
        unsigned int c = pairs[base + i] >> 16;
        atomicAdd(&lc[c & 255], 1);
    }
    __syncthreads();
    int col0 = b << 8;
    if (col0 + t < NU) counts[col0 + t] = lc[t];
}

__global__ void k_scanA(const int* __restrict__ counts, int* __restrict__ sums) {
    __shared__ int wsum[4];
    int t = threadIdx.x;
    int idx = blockIdx.x * 256 + t;
    int v = (idx < NU) ? counts[idx] : 0;
    int total;
    block_excl_scan<4>(v, t, wsum, &total);
    if (t == 0) sums[blockIdx.x] = total;
}

__global__ void k_scanB(int* __restrict__ sums, int nblk, int* __restrict__ offsets) {
    __shared__ int wsum[4];
    int t = threadIdx.x;  // 256
    int v = (t < nblk) ? sums[t] : 0;
    int total;
    int excl = block_excl_scan<4>(v, t, wsum, &total);
    if (t < nblk) sums[t] = excl;
    if (t == 0) offsets[NU] = total;
}

__global__ void k_scanC(const int* __restrict__ counts, const int* __restrict__ sums,
                        int* __restrict__ offsets, float* __restrict__ dinv) {
    __shared__ int wsum[4];
    int t = threadIdx.x;
    int idx = blockIdx.x * 256 + t;
    int v = (idx < NU) ? counts[idx] : 0;
    int excl = block_excl_scan<4>(v, t, wsum, nullptr);
    if (idx < NU) {
        offsets[idx] = sums[blockIdx.x] + excl;
        dinv[idx] = rsqrtf((float)(v + 1));
    }
}

// scatter within bucket window (one block per bucket); csr stored as u16
__global__ void k_scatter(const unsigned int* __restrict__ pairs,
                          const int* __restrict__ bucket_cur, const int* __restrict__ offsets,
                          unsigned short* __restrict__ csr16) {
    __shared__ int lcur[256];
    int b = blockIdx.x, t = threadIdx.x;
    int col0 = b << 8;
    lcur[t] = (col0 + t < NU) ? offsets[col0 + t] : 0;
    __syncthreads();
    int n = bucket_cur[b];
    unsigned int base = (unsigned int)b * CAP;
    for (int i = t; i < n; i += 256) {
        unsigned int pk = pairs[base + i];
        int pos = atomicAdd(&lcur[(pk >> 16) & 255], 1);
        csr16[pos] = (unsigned short)(pk & 0xffffu);
    }
}

// ============ weight folding: WcU = W1*Wu (as [32][128] transposed), WcM = W1*Wm,
//              W2T transpose, bcU = W1*bu + b1, bcM = W1*bm + b1 ============

__global__ void k_fold(const float* __restrict__ Wu, const float* __restrict__ bu,
                       const float* __restrict__ Wm, const float* __restrict__ bm,
                       const float* __restrict__ W1, const float* __restrict__ b1,
                       const float* __restrict__ W2,
                       float* __restrict__ WcUT, float* __restrict__ bcU,
                       float* __restrict__ WcMT, float* __restrict__ bcM,
                       float* __restrict__ W2T) {
    int bid = blockIdx.x, t = threadIdx.x;
    if (bid < 16) {                       // WcUT[k][c], k<32, c<128
        int f = bid * 256 + t;
        int k = f >> 7, c = f & 127;
        float s = 0.f;
        for (int j = 0; j < 128; j++) s += W1[c * 128 + j] * Wu[j * 32 + k];
        WcUT[f] = s;
    } else if (bid < 48) {                // WcMT[k][c], k<64
        int f = (bid - 16) * 256 + t;
        int k = f >> 7, c = f & 127;
        float s = 0.f;
        for (int j = 0; j < 128; j++) s += W1[c * 128 + j] * Wm[j * 64 + k];
        WcMT[f] = s;
    } else if (bid < 112) {               // W2T[k][c] = W2[c][k]
        int f = (bid - 48) * 256 + t;
        int k = f >> 7, c = f & 127;
        W2T[f] = W2[c * 128 + k];
    } else {
        if (t < 128) {
            float s = 0.f;
            for (int j = 0; j < 128; j++) s += W1[t * 128 + j] * bu[j];
            bcU[t] = s + b1[t];
        } else if (t < 256) {
            int c = t - 128;
            float s = 0.f;
            for (int j = 0; j < 128; j++) s += W1[c * 128 + j] * bm[j];
            bcM[c] = s + b1[c];
        }
    }
}

// ============ MFMA B-fragment tables (fp16, lane-ordered) ============
// v_mfma_f32_16x16x32_f16: A[m=lane&15][k=(lane>>4)*8+j]; B[k=(lane>>4)*8+j][n=lane&15]
// fragWcU: [t8][l][j]       (K=32,  1 k-step)   512 groups
// fragWcM: [t8][s][l][j]    (K=64,  2 k-steps) 1024 groups
// fragW2:  [t8][s][l][j]    (K=128, 4 k-steps) 2048 groups
__global__ void k_wfrag(const float* __restrict__ WcUT, const float* __restrict__ WcMT,
                        const float* __restrict__ W2T,
                        _Float16* __restrict__ fragWcU, _Float16* __restrict__ fragWcM,
                        _Float16* __restrict__ fragW2) {
    int g = blockIdx.x * 256 + threadIdx.x;
    if (g >= 3584) return;
    half8 out;
    _Float16* dst;
    if (g < 512) {
        int t8 = g >> 6, l = g & 63;
#pragma unroll
        for (int j = 0; j < 8; j++)
            out[j] = (_Float16)WcUT[((l >> 4) * 8 + j) * 128 + t8 * 16 + (l & 15)];
        dst = &fragWcU[g * 8];
    } else if (g < 1536) {
        int g2 = g - 512;
        int t8 = g2 >> 7, s = (g2 >> 6) & 1, l = g2 & 63;
#pragma unroll
        for (int j = 0; j < 8; j++)
            out[j] = (_Float16)WcMT[(s * 32 + (l >> 4) * 8 + j) * 128 + t8 * 16 + (l & 15)];
        dst = &fragWcM[g2 * 8];
    } else {
        int g2 = g - 1536;
        int t8 = g2 >> 8, s = (g2 >> 6) & 3, l = g2 & 63;
#pragma unroll
        for (int j = 0; j < 8; j++)
            out[j] = (_Float16)W2T[(s * 32 + (l >> 4) * 8 + j) * 128 + t8 * 16 + (l & 15)];
        dst = &fragW2[g2 * 8];
    }
    *(half8*)dst = out;
}

// ============ fp16 PRE-SCALED user features: xs16[n] = dinv[n] * x_user[n] ============

__global__ void k_half(const float* __restrict__ x, const float* __restrict__ dinv,
                       __half2* __restrict__ o, int n2) {
    int i = blockIdx.x * 256 + threadIdx.x;
    if (i < n2) {
        float2 v = ((const float2*)x)[i];
        float s = dinv[i >> 4];   // 16 half2 per node
        o[i] = __floats2half2_rn(v.x * s, v.y * s);
    }
}

// ============ layer-1 aggregation in raw 32-dim feature space ============
// gfull[c] = dinv[c]^2 * x_u[c] + dinv[c] * sum_r dinv[r]*x_u[r]   (table pre-scaled)
// beta[c]  = dinv[c]^2 + dinv[c] * sum_r dinv[r]
// wave per node; neighbor list cached in a register (deg<=64 fast path, mean deg 20);
// half8 gathers: 4 lanes per 64B row -> 16 edge-rows per load instruction
__global__ void k_agg1(const _Float16* __restrict__ xs16, const float* __restrict__ x_user,
                       const int* __restrict__ offsets, const unsigned short* __restrict__ csr,
                       const float* __restrict__ dinv,
                       float* __restrict__ gfull, float* __restrict__ beta) {
    int t = threadIdx.x;
    int l = t & 63, w = t >> 6;
    int n = blockIdx.x * 4 + w;
    int sub = l >> 2, ii = l & 3;   // 16 row-groups x 4 lanes (8 fp16 features each)
    int s = offsets[n], e = offsets[n + 1];
    int deg = e - s;
    int idx = (l < deg) ? (int)csr[s + l] : 0;
    const half8* x8 = (const half8*)xs16;   // row r at x8[r*4 + ii]
    float acc[8];
#pragma unroll
    for (int k = 0; k < 8; k++) acc[k] = 0.f;
    float sacc = 0.f;
    int dcap = deg <= 64 ? deg : 64;
    int j = 0;
    for (; j + 16 <= dcap; j += 16) {
        int r = __shfl(idx, j + sub, 64);
        half8 a = x8[r * 4 + ii];
#pragma unroll
        for (int k = 0; k < 8; k++) acc[k] += (float)a[k];
        if (ii == 0) sacc += dinv[r];
    }
    if (j + sub < dcap) {
        int r = __shfl(idx, j + sub, 64);
        half8 a = x8[r * 4 + ii];
#pragma unroll
        for (int k = 0; k < 8; k++) acc[k] += (float)a[k];
        if (ii == 0) sacc += dinv[r];
    }
    for (int jj = 64 + sub; jj < deg; jj += 16) {   // deg>64 fallback (~10 sigma, never hit)
        int r = (int)csr[s + jj];
        half8 a = x8[r * 4 + ii];
#pragma unroll
        for (int k = 0; k < 8; k++) acc[k] += (float)a[k];
        if (ii == 0) sacc += dinv[r];
    }
#pragma unroll
    for (int k = 0; k < 8; k++) {
        acc[k] += __shfl_xor(acc[k], 4, 64);
        acc[k] += __shfl_xor(acc[k], 8, 64);
        acc[k] += __shfl_xor(acc[k], 16, 64);
        acc[k] += __shfl_xor(acc[k], 32, 64);
    }
    sacc += __shfl_xor(sacc, 4, 64);
    sacc += __shfl_xor(sacc, 8, 64);
    sacc += __shfl_xor(sacc, 16, 64);
    sacc += __shfl_xor(sacc, 32, 64);
    float dn = dinv[n];
    if (sub == 0) {   // lanes 0..3 write 8 features each (f = ii*8+k)
        const float4* xu4 = (const float4*)x_user;
        float4 xa = xu4[n * 8 + ii * 2];
        float4 xb = xu4[n * 8 + ii * 2 + 1];
        float4 oa, ob;
        oa.x = dn * dn * xa.x + dn * acc[0];
        oa.y = dn * dn * xa.y + dn * acc[1];
        oa.z = dn * dn * xa.z + dn * acc[2];
        oa.w = dn * dn * xa.w + dn * acc[3];
        ob.x = dn * dn * xb.x + dn * acc[4];
        ob.y = dn * dn * xb.y + dn * acc[5];
        ob.z = dn * dn * xb.z + dn * acc[6];
        ob.w = dn * dn * xb.w + dn * acc[7];
        float4* g4 = (float4*)gfull;
        g4[n * 8 + ii * 2] = oa;
        g4[n * 8 + ii * 2 + 1] = ob;
    }
    if (l == 0) beta[n] = dn * dn + dn * sacc;
}

// ============ fused user chain (MFMA): (gfull @ WcU + beta*bcU) -> relu -> @W2 + b2, *dinv -> fp16
__global__ void __launch_bounds__(256) k_user(
        const float* __restrict__ gfull, const float* __restrict__ beta,
        const _Float16* __restrict__ fragWcU, const float* __restrict__ bcU,
        const _Float16* __restrict__ fragW2, const float* __restrict__ b2,
        const float* __restrict__ dinv, _Float16* __restrict__ h2p) {
    __shared__ _Float16 xs[64 * 40];   // 64 rows x K=32 (pad 40)
    __shared__ _Float16 ys[64 * 136];  // 64 rows x 128 (pad 136)
    int t = threadIdx.x;
    int n0 = blockIdx.x * 64;
    {   // stage gfull -> xs fp16 (wave-local rows)
        int r = t >> 2, c0 = (t & 3) * 8;
        int n = n0 + r;
        float4 a = make_float4(0.f, 0.f, 0.f, 0.f), b = a;
        if (n < NU) {
            const float4* g4 = (const float4*)gfull;
            a = g4[n * 8 + (c0 >> 2)];
            b = g4[n * 8 + (c0 >> 2) + 1];
        }
        half8 h;
        h[0] = (_Float16)a.x; h[1] = (_Float16)a.y; h[2] = (_Float16)a.z; h[3] = (_Float16)a.w;
        h[4] = (_Float16)b.x; h[5] = (_Float16)b.y; h[6] = (_Float16)b.z; h[7] = (_Float16)b.w;
        *(half8*)&xs[r * 40 + c0] = h;
    }
    __syncthreads();
    int l = t & 63, w = t >> 6;
    int lr = l & 15, lq = l >> 4;
    // GEMM1: K=32, one mfma step per n-tile
    half8 af = *(half8*)&xs[(16 * w + lr) * 40 + lq * 8];
    const half8* fU = (const half8*)fragWcU;
    f32x4 zero = {0.f, 0.f, 0.f, 0.f};
    f32x4 acc[8];
#pragma unroll
    for (int t8 = 0; t8 < 8; t8++) {
        half8 bf = fU[t8 * 64 + l];
        acc[t8] = __builtin_amdgcn_mfma_f32_16x16x32_f16(af, bf, zero, 0, 0, 0);
    }
    float betav[4];
#pragma unroll
    for (int r = 0; r < 4; r++) {
        int n = n0 + 16 * w + lq * 4 + r;
        betav[r] = (n < NU) ? beta[n] : 0.f;
    }
#pragma unroll
    for (int t8 = 0; t8 < 8; t8++) {
        float bc = bcU[16 * t8 + lr];
#pragma unroll
        for (int r = 0; r < 4; r++) {
            float v = fmaxf(acc[t8][r] + betav[r] * bc, 0.f);
            ys[(16 * w + lq * 4 + r) * 136 + 16 * t8 + lr] = (_Float16)v;
        }
    }
    __syncthreads();
    // GEMM2: K=128, 4 mfma steps
    f32x4 acc2[8];
#pragma unroll
    for (int t8 = 0; t8 < 8; t8++) acc2[t8] = zero;
    const half8* fW = (const half8*)fragW2;
#pragma unroll
    for (int s = 0; s < 4; s++) {
        half8 a2 = *(half8*)&ys[(16 * w + lr) * 136 + s * 32 + lq * 8];
#pragma unroll
        for (int t8 = 0; t8 < 8; t8++) {
            half8 bf = fW[(t8 * 4 + s) * 64 + l];
            acc2[t8] = __builtin_amdgcn_mfma_f32_16x16x32_f16(a2, bf, acc2[t8], 0, 0, 0);
        }
    }
#pragma unroll
    for (int r = 0; r < 4; r++) {
        int n = n0 + 16 * w + lq * 4 + r;
        if (n < NU) {
            float s = dinv[n];
#pragma unroll
            for (int t8 = 0; t8 < 8; t8++) {
                int c = 16 * t8 + lr;
                h2p[n * 128 + c] = (_Float16)((acc2[t8][r] + b2[c]) * s);
            }
        }
    }
}

// ============ fused movie chain (MFMA): (x_movie @ WcM + bcM) -> relu -> @W2 + b2
//              -> relu -> project with We_m -> P   (h2m round-trip + k_mproj eliminated)
__global__ void __launch_bounds__(256) k_movie(
        const float* __restrict__ xm,
        const _Float16* __restrict__ fragWcM, const float* __restrict__ bcM,
        const _Float16* __restrict__ fragW2, const float* __restrict__ b2,
        const float* __restrict__ We, float* __restrict__ P) {
    __shared__ _Float16 xs[64 * 72];   // 64 rows x K=64 (pad 72)
    __shared__ _Float16 ys[64 * 136];
    int t = threadIdx.x;
    int n0 = blockIdx.x * 64;
    {   // stage x_movie -> xs fp16
        int r = t >> 2, c0 = (t & 3) * 16;
        int n = n0 + r;
        float4 a = make_float4(0.f, 0.f, 0.f, 0.f), b = a, c = a, d = a;
        if (n < NM) {
            const float4* g4 = (const float4*)xm;
            a = g4[n * 16 + (c0 >> 2)];
            b = g4[n * 16 + (c0 >> 2) + 1];
            c = g4[n * 16 + (c0 >> 2) + 2];
            d = g4[n * 16 + (c0 >> 2) + 3];
        }
        half8 h0, h1;
        h0[0] = (_Float16)a.x; h0[1] = (_Float16)a.y; h0[2] = (_Float16)a.z; h0[3] = (_Float16)a.w;
        h0[4] = (_Float16)b.x; h0[5] = (_Float16)b.y; h0[6] = (_Float16)b.z; h0[7] = (_Float16)b.w;
        h1[0] = (_Float16)c.x; h1[1] = (_Float16)c.y; h1[2] = (_Float16)c.z; h1[3] = (_Float16)c.w;
        h1[4] = (_Float16)d.x; h1[5] = (_Float16)d.y; h1[6] = (_Float16)d.z; h1[7] = (_Float16)d.w;
        *(half8*)&xs[r * 72 + c0] = h0;
        *(half8*)&xs[r * 72 + c0 + 8] = h1;
    }
    __syncthreads();
    int l = t & 63, w = t >> 6;
    int lr = l & 15, lq = l >> 4;
    const half8* fM = (const half8*)fragWcM;
    f32x4 zero = {0.f, 0.f, 0.f, 0.f};
    f32x4 acc[8];
#pragma unroll
    for (int t8 = 0; t8 < 8; t8++) acc[t8] = zero;
#pragma unroll
    for (int s = 0; s < 2; s++) {
        half8 af = *(half8*)&xs[(16 * w + lr) * 72 + s * 32 + lq * 8];
#pragma unroll
        for (int t8 = 0; t8 < 8; t8++) {
            half8 bf = fM[(t8 * 2 + s) * 64 + l];
            acc[t8] = __builtin_amdgcn_mfma_f32_16x16x32_f16(af, bf, acc[t8], 0, 0, 0);
        }
    }
#pragma unroll
    for (int t8 = 0; t8 < 8; t8++) {
        float bc = bcM[16 * t8 + lr];
#pragma unroll
        for (int r = 0; r < 4; r++) {
            float v = fmaxf(acc[t8][r] + bc, 0.f);
            ys[(16 * w + lq * 4 + r) * 136 + 16 * t8 + lr] = (_Float16)v;
        }
    }
    __syncthreads();
    f32x4 acc2[8];
#pragma unroll
    for (int t8 = 0; t8 < 8; t8++) acc2[t8] = zero;
    const half8* fW = (const half8*)fragW2;
#pragma unroll
    for (int s = 0; s < 4; s++) {
        half8 a2 = *(half8*)&ys[(16 * w + lr) * 136 + s * 32 + lq * 8];
#pragma unroll
        for (int t8 = 0; t8 < 8; t8++) {
            half8 bf = fW[(t8 * 4 + s) * 64 + l];
            acc2[t8] = __builtin_amdgcn_mfma_f32_16x16x32_f16(a2, bf, acc2[t8], 0, 0, 0);
        }
    }
    // fused epilogue: relu(acc2 + b2), project with We movie half (fp32 for precision),
    // reduce across the 16 lanes that hold a row's features, write P directly.
    float v[8][4];
#pragma unroll
    for (int t8 = 0; t8 < 8; t8++) {
        float bv = b2[16 * t8 + lr];
#pragma unroll
        for (int r = 0; r < 4; r++) v[t8][r] = fmaxf(acc2[t8][r] + bv, 0.f);
    }
#pragma unroll
    for (int q = 0; q < NC; q++) {
        float pq[4] = {0.f, 0.f, 0.f, 0.f};
#pragma unroll
        for (int t8 = 0; t8 < 8; t8++) {
            float wv = We[q * 256 + 128 + 16 * t8 + lr];
#pragma unroll
            for (int r = 0; r < 4; r++) pq[r] += wv * v[t8][r];
        }
#pragma unroll
        for (int r = 0; r < 4; r++) {
            float sv = pq[r];
            sv += __shfl_xor(sv, 1, 64);
            sv += __shfl_xor(sv, 2, 64);
            sv += __shfl_xor(sv, 4, 64);
            sv += __shfl_xor(sv, 8, 64);
            int n = n0 + 16 * w + lq * 4 + r;
            if (lr == 0 && n < NM) P[(size_t)(NU + n) * NC + q] = sv;
        }
    }
}

// ============ layer-2 aggregation (fp16 pre-scaled table) + fused projection -> P_u (with be)
// wave per node; neighbor list cached in a register (deg<=64 fast path);
// half8 gathers: 16 lanes per 256B row -> 4 edge-rows per load instruction, 8 edges in flight
__global__ void k_agg2(const _Float16* __restrict__ hv, const int* __restrict__ offsets,
                       const unsigned short* __restrict__ csr, const float* __restrict__ dinv,
                       const float* __restrict__ We, const float* __restrict__ be,
                       float* __restrict__ P) {
    int t = threadIdx.x;
    int l = t & 63, w = t >> 6;
    int n = blockIdx.x * 4 + w;
    int g = l >> 4, i = l & 15;   // 4 row-groups x 16 lanes (8 fp16 features each)
    int s = offsets[n], e = offsets[n + 1];
    int deg = e - s;
    int idx = (l < deg) ? (int)csr[s + l] : 0;
    const half8* hv8 = (const half8*)hv;   // row r at hv8[r*16 + i]
    float acc[8];
    if (g == 0) {   // self term (added once)
        half8 sv = hv8[n * 16 + i];
#pragma unroll
        for (int k = 0; k < 8; k++) acc[k] = (float)sv[k];
    } else {
#pragma unroll
        for (int k = 0; k < 8; k++) acc[k] = 0.f;
    }
    int dcap = deg <= 64 ? deg : 64;
    int j = 0;
    for (; j + 8 <= dcap; j += 8) {
        int r0 = __shfl(idx, j + g, 64);
        int r1 = __shfl(idx, j + 4 + g, 64);
        half8 a = hv8[r0 * 16 + i];
        half8 b = hv8[r1 * 16 + i];
#pragma unroll
        for (int k = 0; k < 8; k++) acc[k] += (float)a[k] + (float)b[k];
    }
    if (j + 4 <= dcap) {
        int r0 = __shfl(idx, j + g, 64);
        half8 a = hv8[r0 * 16 + i];
#pragma unroll
        for (int k = 0; k < 8; k++) acc[k] += (float)a[k];
        j += 4;
    }
    if (j + g < dcap) {
        int r0 = __shfl(idx, j + g, 64);
        half8 a = hv8[r0 * 16 + i];
#pragma unroll
        for (int k = 0; k < 8; k++) acc[k] += (float)a[k];
    }
    for (int jj = 64 + g; jj < deg; jj += 4) {   // deg>64 fallback (~10 sigma, never hit)
        int r0 = (int)csr[s + jj];
        half8 a = hv8[r0 * 16 + i];
#pragma unroll
        for (int k = 0; k < 8; k++) acc[k] += (float)a[k];
    }
#pragma unroll
    for (int k = 0; k < 8; k++) {
        acc[k] += __shfl_xor(acc[k], 16, 64);
        acc[k] += __shfl_xor(acc[k], 32, 64);
    }
    float dn = dinv[n];
    float v[8];
#pragma unroll
    for (int k = 0; k < 8; k++) v[k] = fmaxf(acc[k] * dn, 0.f);
    // projection: each 16-lane group handles q = g, g+4, g+8 (NC=10)
    for (int q = g; q < NC; q += 4) {
        const float4* wq = (const float4*)&We[q * 256 + i * 8];
        float4 w0 = wq[0], w1 = wq[1];
        float p = w0.x * v[0] + w0.y * v[1] + w0.z * v[2] + w0.w * v[3]
                + w1.x * v[4] + w1.y * v[5] + w1.z * v[6] + w1.w * v[7];
        p += __shfl_xor(p, 1, 64);
        p += __shfl_xor(p, 2, 64);
        p += __shfl_xor(p, 4, 64);
        p += __shfl_xor(p, 8, 64);
        if (i == 0) P[n * NC + q] = p + be[q];
    }
}

// ============ edge output: out[e] = P[row[e]] + P[NU + col[e]] ============
__global__ void k_edge_out(const int* __restrict__ row, const int* __restrict__ col,
                           const float* __restrict__ P, float* __restrict__ out, int E) {
    __shared__ float ls[256 * 11];
    int t = threadIdx.x;
    int e0 = blockIdx.x * 256;
    int e = e0 + t;
    if (e < E) {
        int r = row[e], c = col[e];
        const float2* pu = (const float2*)(P + (size_t)r * NC);
        const float2* pm = (const float2*)(P + (size_t)(NU + c) * NC);
#pragma unroll
        for (int q = 0; q < 5; q++) {
            float2 a = pu[q], b = pm[q];
            ls[t * 11 + 2 * q] = a.x + b.x;
            ls[t * 11 + 2 * q + 1] = a.y + b.y;
        }
    }
    __syncthreads();
    int nvals = (E - e0 < 256 ? E - e0 : 256) * NC;
    size_t base = (size_t)e0 * NC;
    for (int k = t; k < nvals; k += 256) {
        int ee = k / NC, q = k - ee * NC;
        out[base + k] = ls[ee * 11 + q];
    }
}

extern "C" void kernel_launch(void* const* d_in, const int* in_sizes, int n_in,
                              void* d_out, int out_size, void* d_ws, size_t ws_size,
                              hipStream_t stream) {
    const float* x_user  = (const float*)d_in[0];
    const float* x_movie = (const float*)d_in[1];
    const int*   ei      = (const int*)d_in[2];
    const float* Wu = (const float*)d_in[3];
    const float* bu = (const float*)d_in[4];
    const float* Wm = (const float*)d_in[5];
    const float* bm = (const float*)d_in[6];
    const float* W1 = (const float*)d_in[7];
    const float* b1 = (const float*)d_in[8];
    const float* W2 = (const float*)d_in[9];
    const float* b2 = (const float*)d_in[10];
    const float* We = (const float*)d_in[11];
    const float* be = (const float*)d_in[12];
    float* out = (float*)d_out;

    int E = in_sizes[2] / 2;
    const int* row = ei;
    const int* col = ei + E;

    char* p = (char*)d_ws;
    auto alloc = [&](size_t bytes) -> void* {
        void* r = (void*)p;
        p += (bytes + 255) & ~(size_t)255;
        return r;
    };
    int*            counts     = (int*)alloc((size_t)NU * 4);
    int*            offsets    = (int*)alloc((size_t)(NU + 1) * 4);
    unsigned short* csr16      = (unsigned short*)alloc((size_t)E * 2);
    unsigned int*   pairs      = (unsigned int*)alloc((size_t)NB * CAP * 4);
    int*            bucket_cur = (int*)alloc((size_t)NB * 4);
    float*          dinv       = (float*)alloc((size_t)NU * 4);
    float*          beta       = (float*)alloc((size_t)NU * 4);
    int*            sums       = (int*)alloc((size_t)256 * 4);
    float*          WcUT       = (float*)alloc((size_t)FU * HD * 4);
    float*          WcMT       = (float*)alloc((size_t)FM * HD * 4);
    float*          W2T        = (float*)alloc((size_t)HD * HD * 4);
    float*          bcU        = (float*)alloc((size_t)HD * 4);
    float*          bcM       = (float*)alloc((size_t)HD * 4);
    _Float16*       fragWcU    = (_Float16*)alloc((size_t)4096 * 2);
    _Float16*       fragWcM    = (_Float16*)alloc((size_t)8192 * 2);
    _Float16*       fragW2     = (_Float16*)alloc((size_t)16384 * 2);
    __half2*        xs16       = (__half2*)alloc((size_t)NU * FU * 2);
    float*          gfull      = (float*)alloc((size_t)NU * FU * 4);
    _Float16*       h2p        = (_Float16*)alloc((size_t)NU * HD * 2);
    float*          P          = (float*)alloc((size_t)NN * NC * 4);

    const int tb = 256;
    const int nscan = (NU + 255) / 256;  // 196

    hipMemsetAsync(bucket_cur, 0, (size_t)NB * 4, stream);
    k_bucket<<<(E + CHUNK - 1) / CHUNK, 256, 0, stream>>>(row, col, E, bucket_cur, pairs);
    k_bcount<<<NB, 256, 0, stream>>>(pairs, bucket_cur, counts);
    k_scanA<<<nscan, 256, 0, stream>>>(counts, sums);
    k_scanB<<<1, 256, 0, stream>>>(sums, nscan, offsets);
    k_scanC<<<nscan, 256, 0, stream>>>(counts, sums, offsets, dinv);
    k_scatter<<<NB, 256, 0, stream>>>(pairs, bucket_cur, offsets, csr16);

    k_fold<<<113, 256, 0, stream>>>(Wu, bu, Wm, bm, W1, b1, W2, WcUT, bcU, WcMT, bcM, W2T);
    k_wfrag<<<14, 256, 0, stream>>>(WcUT, WcMT, W2T, fragWcU, fragWcM, fragW2);
    k_half<<<(NU * FU / 2 + 255) / 256, 256, 0, stream>>>(x_user, dinv, xs16, NU * FU / 2);

    k_agg1<<<NU / 4, 256, 0, stream>>>((const _Float16*)xs16, x_user, offsets, csr16, dinv,
                                       gfull, beta);

    k_user<<<(NU + 63) / 64, 256, 0, stream>>>(gfull, beta, fragWcU, bcU, fragW2, b2, dinv, h2p);
    k_movie<<<(NM + 63) / 64, 256, 0, stream>>>(x_movie, fragWcM, bcM, fragW2, b2, We, P);

    k_agg2<<<NU / 4, 256, 0, stream>>>((const _Float16*)h2p, offsets, csr16, dinv, We, be, P);

    k_edge_out<<<(E + tb - 1) / tb, tb, 0, stream>>>(row, col, P, out, E);
}

// Round 2
// 271.309 us; speedup vs baseline: 1.1713x; 1.0297x over previous
//
#include <hip/hip_runtime.h>
#include <hip/hip_fp16.h>

#define NU 50000
#define NM 50000
#define NN 100000
#define FU 32
#define FM 64
#define HD 128
#define NC 10
#define PSTR 12     // padded P row stride (floats), 48B = 16B-aligned

#define NB 196      // buckets of 256 destination cols
#define CAP 8192    // per-bucket staging capacity (mean 5102, +43 sigma)
#define CHUNK 4096  // edges per k_bucket block

typedef __attribute__((ext_vector_type(8))) _Float16 half8;
typedef __attribute__((ext_vector_type(4))) float f32x4;

// ============ scan helpers ============

__device__ inline int wave_incl_scan(int x, int l) {
#pragma unroll
    for (int d = 1; d < 64; d <<= 1) {
        int u = __shfl_up(x, d, 64);
        if (l >= d) x += u;
    }
    return x;
}

template <int NWAVE>
__device__ inline int block_excl_scan(int v, int t, int* wsum, int* out_total) {
    int l = t & 63, w = t >> 6;
    int inc = wave_incl_scan(v, l);
    if (l == 63) wsum[w] = inc;
    __syncthreads();
    int base = 0;
    int tot = 0;
#pragma unroll
    for (int i = 0; i < NWAVE; i++) {
        int s = wsum[i];
        if (i < w) base += s;
        tot += s;
    }
    if (out_total) *out_total = tot;
    return base + inc - v;
}

// ============ bucketed CSR build ============
// pairs[b*CAP + i] = row | (col<<16), grouped by bucket b = col>>8

__global__ void k_bucket(const int* __restrict__ row, const int* __restrict__ col, int E,
                         int* __restrict__ bucket_cur, unsigned int* __restrict__ pairs) {
    __shared__ int hist[NB];
    __shared__ int lofs[NB];
    __shared__ int gbase[NB];
    __shared__ int lcur[NB];
    __shared__ int wsum[4];
    __shared__ unsigned int stage[CHUNK];
    int t = threadIdx.x;
    int e0 = blockIdx.x * CHUNK;
    int cnt = min(CHUNK, E - e0);
    for (int i = t; i < NB; i += 256) hist[i] = 0;
    __syncthreads();
    unsigned int pk[CHUNK / 256];
#pragma unroll
    for (int i = 0; i < CHUNK / 256; i++) {
        int k = i * 256 + t;
        if (k < cnt) {
            unsigned int r = (unsigned int)row[e0 + k];
            unsigned int c = (unsigned int)col[e0 + k];
            pk[i] = r | (c << 16);
            atomicAdd(&hist[c >> 8], 1);
        }
    }
    __syncthreads();
    int v = (t < NB) ? hist[t] : 0;
    int excl = block_excl_scan<4>(v, t, wsum, nullptr);
    if (t < NB) {
        lofs[t] = excl;
        lcur[t] = excl;
        gbase[t] = atomicAdd(&bucket_cur[t], v);
    }
    __syncthreads();
#pragma unroll
    for (int i = 0; i < CHUNK / 256; i++) {
        int k = i * 256 + t;
        if (k < cnt) {
            int pos = atomicAdd(&lcur[pk[i] >> 24], 1);  // (c>>8) == pk>>24
            stage[pos] = pk[i];
        }
    }
    __syncthreads();
    int w = t >> 6, l = t & 63;
    for (int b = w; b < NB; b += 4) {
        int start = lofs[b], n = hist[b];
        unsigned int g = (unsigned int)b * CAP + (unsigned int)gbase[b];
        for (int i = l; i < n; i += 64) pairs[g + i] = stage[start + i];
    }
}

// per-col degree counts from bucketed pairs (one block per bucket)
__global__ void k_bcount(const unsigned int* __restrict__ pairs,
                         const int* __restrict__ bucket_cur, int* __restrict__ counts) {
    __shared__ int lc[256];
    int b = blockIdx.x, t = threadIdx.x;
    lc[t] = 0;
    __syncthreads();
    int n = bucket_cur[b];
    unsigned int base = (unsigned int)b * CAP;
    for (int i = t; i < n; i += 256) {
        unsigned int c = pairs[base + i] >> 16;
        atomicAdd(&lc[c & 255], 1);
    }
    __syncthreads();
    int col0 = b << 8;
    if (col0 + t < NU) counts[col0 + t] = lc[t];
}

__global__ void k_scanA(const int* __restrict__ counts, int* __restrict__ sums) {
    __shared__ int wsum[4];
    int t = threadIdx.x;
    int idx = blockIdx.x * 256 + t;
    int v = (idx < NU) ? counts[idx] : 0;
    int total;
    block_excl_scan<4>(v, t, wsum, &total);
    if (t == 0) sums[blockIdx.x] = total;
}

// also zeroes the NU "zero rows" used by the aggregation kernels
__global__ void k_scanB(int* __restrict__ sums, int nblk, int* __restrict__ offsets,
                        float* __restrict__ dinv, float4* __restrict__ zx,
                        float4* __restrict__ zh) {
    __shared__ int wsum[4];
    int t = threadIdx.x;  // 256
    int v = (t < nblk) ? sums[t] : 0;
    int total;
    int excl = block_excl_scan<4>(v, t, wsum, &total);
    if (t < nblk) sums[t] = excl;
    if (t == 0) {
        offsets[NU] = total;
        dinv[NU] = 0.f;
    }
    float4 z = make_float4(0.f, 0.f, 0.f, 0.f);
    if (t < 4) zx[t] = z;    // xs16 row NU (64 B)
    if (t < 16) zh[t] = z;   // h2p row NU (256 B)
}

__global__ void k_scanC(const int* __restrict__ counts, const int* __restrict__ sums,
                        int* __restrict__ offsets, float* __restrict__ dinv) {
    __shared__ int wsum[4];
    int t = threadIdx.x;
    int idx = blockIdx.x * 256 + t;
    int v = (idx < NU) ? counts[idx] : 0;
    int excl = block_excl_scan<4>(v, t, wsum, nullptr);
    if (idx < NU) {
        offsets[idx] = sums[blockIdx.x] + excl;
        dinv[idx] = rsqrtf((float)(v + 1));
    }
}

// scatter within bucket window (one block per bucket); csr stored as u16
__global__ void k_scatter(const unsigned int* __restrict__ pairs,
                          const int* __restrict__ bucket_cur, const int* __restrict__ offsets,
                          unsigned short* __restrict__ csr16) {
    __shared__ int lcur[256];
    int b = blockIdx.x, t = threadIdx.x;
    int col0 = b << 8;
    lcur[t] = (col0 + t < NU) ? offsets[col0 + t] : 0;
    __syncthreads();
    int n = bucket_cur[b];
    unsigned int base = (unsigned int)b * CAP;
    for (int i = t; i < n; i += 256) {
        unsigned int pk = pairs[base + i];
        int pos = atomicAdd(&lcur[(pk >> 16) & 255], 1);
        csr16[pos] = (unsigned short)(pk & 0xffffu);
    }
}

// ============ weight folding: WcU = W1*Wu (as [32][128] transposed), WcM = W1*Wm,
//              W2T transpose, bcU = W1*bu + b1, bcM = W1*bm + b1 ============

__global__ void k_fold(const float* __restrict__ Wu, const float* __restrict__ bu,
                       const float* __restrict__ Wm, const float* __restrict__ bm,
                       const float* __restrict__ W1, const float* __restrict__ b1,
                       const float* __restrict__ W2,
                       float* __restrict__ WcUT, float* __restrict__ bcU,
                       float* __restrict__ WcMT, float* __restrict__ bcM,
                       float* __restrict__ W2T) {
    int bid = blockIdx.x, t = threadIdx.x;
    if (bid < 16) {                       // WcUT[k][c], k<32, c<128
        int f = bid * 256 + t;
        int k = f >> 7, c = f & 127;
        float s = 0.f;
        for (int j = 0; j < 128; j++) s += W1[c * 128 + j] * Wu[j * 32 + k];
        WcUT[f] = s;
    } else if (bid < 48) {                // WcMT[k][c], k<64
        int f = (bid - 16) * 256 + t;
        int k = f >> 7, c = f & 127;
        float s = 0.f;
        for (int j = 0; j < 128; j++) s += W1[c * 128 + j] * Wm[j * 64 + k];
        WcMT[f] = s;
    } else if (bid < 112) {               // W2T[k][c] = W2[c][k]
        int f = (bid - 48) * 256 + t;
        int k = f >> 7, c = f & 127;
        W2T[f] = W2[c * 128 + k];
    } else {
        if (t < 128) {
            float s = 0.f;
            for (int j = 0; j < 128; j++) s += W1[t * 128 + j] * bu[j];
            bcU[t] = s + b1[t];
        } else if (t < 256) {
            int c = t - 128;
            float s = 0.f;
            for (int j = 0; j < 128; j++) s += W1[c * 128 + j] * bm[j];
            bcM[c] = s + b1[c];
        }
    }
}

// ============ MFMA B-fragment tables (fp16, lane-ordered) ============
__global__ void k_wfrag(const float* __restrict__ WcUT, const float* __restrict__ WcMT,
                        const float* __restrict__ W2T,
                        _Float16* __restrict__ fragWcU, _Float16* __restrict__ fragWcM,
                        _Float16* __restrict__ fragW2) {
    int g = blockIdx.x * 256 + threadIdx.x;
    if (g >= 3584) return;
    half8 out;
    _Float16* dst;
    if (g < 512) {
        int t8 = g >> 6, l = g & 63;
#pragma unroll
        for (int j = 0; j < 8; j++)
            out[j] = (_Float16)WcUT[((l >> 4) * 8 + j) * 128 + t8 * 16 + (l & 15)];
        dst = &fragWcU[g * 8];
    } else if (g < 1536) {
        int g2 = g - 512;
        int t8 = g2 >> 7, s = (g2 >> 6) & 1, l = g2 & 63;
#pragma unroll
        for (int j = 0; j < 8; j++)
            out[j] = (_Float16)WcMT[(s * 32 + (l >> 4) * 8 + j) * 128 + t8 * 16 + (l & 15)];
        dst = &fragWcM[g2 * 8];
    } else {
        int g2 = g - 1536;
        int t8 = g2 >> 8, s = (g2 >> 6) & 3, l = g2 & 63;
#pragma unroll
        for (int j = 0; j < 8; j++)
            out[j] = (_Float16)W2T[(s * 32 + (l >> 4) * 8 + j) * 128 + t8 * 16 + (l & 15)];
        dst = &fragW2[g2 * 8];
    }
    *(half8*)dst = out;
}

// ============ fp16 PRE-SCALED user features: xs16[n] = dinv[n] * x_user[n] ============

__global__ void k_half(const float* __restrict__ x, const float* __restrict__ dinv,
                       __half2* __restrict__ o, int n2) {
    int i = blockIdx.x * 256 + threadIdx.x;
    if (i < n2) {
        float2 v = ((const float2*)x)[i];
        float s = dinv[i >> 4];   // 16 half2 per node
        o[i] = __floats2half2_rn(v.x * s, v.y * s);
    }
}

// ============ layer-1 aggregation in raw 32-dim feature space ============
// slot list = csr neighbors + self at slot deg + zero-row padding (row NU, dinv[NU]=0).
// Table pre-scaled by dinv, so dn * sum(slots) = dn^2*x[n] + dn*sum dinv[r]x[r] exactly.
// 16 row-groups x 4 lanes (8 fp16 features each); 2 gathers in flight, no tail.
__global__ void k_agg1(const _Float16* __restrict__ xs16,
                       const int* __restrict__ offsets, const unsigned short* __restrict__ csr,
                       const float* __restrict__ dinv,
                       float* __restrict__ gfull, float* __restrict__ beta) {
    int t = threadIdx.x;
    int l = t & 63, w = t >> 6;
    int n = blockIdx.x * 4 + w;
    int sub = l >> 2, ii = l & 3;
    int s = offsets[n], e = offsets[n + 1];
    int deg = e - s;
    int dtot = deg + 1;   // + self slot
    int idx = (l < deg) ? (int)csr[s + l] : (l == deg ? n : NU);
    const half8* x8 = (const half8*)xs16;   // row r at x8[r*4 + ii]
    int r0 = __shfl(idx, sub, 64);
    int r1 = __shfl(idx, 16 + sub, 64);
    half8 a = x8[r0 * 4 + ii];
    half8 b = x8[r1 * 4 + ii];
    half8 q = a + b;    // depth-1 fp16 pair
    float acc[8];
#pragma unroll
    for (int k = 0; k < 8; k++) acc[k] = (float)q[k];
    float sacc = 0.f;
    if (ii == 0) sacc = dinv[r0] + dinv[r1];   // dinv[NU] = 0
    if (__builtin_expect(dtot > 32, 0)) {      // ~0.4% of nodes
        for (int jj = 32 + sub; jj < dtot; jj += 16) {
            int rr = (jj < deg) ? (int)csr[s + jj] : n;
            half8 aa = x8[rr * 4 + ii];
#pragma unroll
            for (int k = 0; k < 8; k++) acc[k] += (float)aa[k];
            if (ii == 0) sacc += dinv[rr];
        }
    }
#pragma unroll
    for (int k = 0; k < 8; k++) {
        acc[k] += __shfl_xor(acc[k], 4, 64);
        acc[k] += __shfl_xor(acc[k], 8, 64);
        acc[k] += __shfl_xor(acc[k], 16, 64);
        acc[k] += __shfl_xor(acc[k], 32, 64);
    }
    sacc += __shfl_xor(sacc, 4, 64);
    sacc += __shfl_xor(sacc, 8, 64);
    sacc += __shfl_xor(sacc, 16, 64);
    sacc += __shfl_xor(sacc, 32, 64);
    float dn = dinv[n];
    if (sub == 0) {   // lanes 0..3 write 8 features each (f = ii*8+k)
        float4 oa, ob;
        oa.x = dn * acc[0]; oa.y = dn * acc[1]; oa.z = dn * acc[2]; oa.w = dn * acc[3];
        ob.x = dn * acc[4]; ob.y = dn * acc[5]; ob.z = dn * acc[6]; ob.w = dn * acc[7];
        float4* g4 = (float4*)gfull;
        g4[n * 8 + ii * 2] = oa;
        g4[n * 8 + ii * 2 + 1] = ob;
    }
    if (l == 0) beta[n] = dn * sacc;
}

// ============ fused user chain (MFMA): (gfull @ WcU + beta*bcU) -> relu -> @W2 + b2, *dinv -> fp16
__global__ void __launch_bounds__(256) k_user(
        const float* __restrict__ gfull, const float* __restrict__ beta,
        const _Float16* __restrict__ fragWcU, const float* __restrict__ bcU,
        const _Float16* __restrict__ fragW2, const float* __restrict__ b2,
        const float* __restrict__ dinv, _Float16* __restrict__ h2p) {
    __shared__ _Float16 xs[64 * 40];   // 64 rows x K=32 (pad 40)
    __shared__ _Float16 ys[64 * 136];  // 64 rows x 128 (pad 136)
    int t = threadIdx.x;
    int n0 = blockIdx.x * 64;
    {   // stage gfull -> xs fp16 (wave-local rows)
        int r = t >> 2, c0 = (t & 3) * 8;
        int n = n0 + r;
        float4 a = make_float4(0.f, 0.f, 0.f, 0.f), b = a;
        if (n < NU) {
            const float4* g4 = (const float4*)gfull;
            a = g4[n * 8 + (c0 >> 2)];
            b = g4[n * 8 + (c0 >> 2) + 1];
        }
        half8 h;
        h[0] = (_Float16)a.x; h[1] = (_Float16)a.y; h[2] = (_Float16)a.z; h[3] = (_Float16)a.w;
        h[4] = (_Float16)b.x; h[5] = (_Float16)b.y; h[6] = (_Float16)b.z; h[7] = (_Float16)b.w;
        *(half8*)&xs[r * 40 + c0] = h;
    }
    __syncthreads();
    int l = t & 63, w = t >> 6;
    int lr = l & 15, lq = l >> 4;
    // GEMM1: K=32, one mfma step per n-tile
    half8 af = *(half8*)&xs[(16 * w + lr) * 40 + lq * 8];
    const half8* fU = (const half8*)fragWcU;
    f32x4 zero = {0.f, 0.f, 0.f, 0.f};
    f32x4 acc[8];
#pragma unroll
    for (int t8 = 0; t8 < 8; t8++) {
        half8 bf = fU[t8 * 64 + l];
        acc[t8] = __builtin_amdgcn_mfma_f32_16x16x32_f16(af, bf, zero, 0, 0, 0);
    }
    float betav[4];
#pragma unroll
    for (int r = 0; r < 4; r++) {
        int n = n0 + 16 * w + lq * 4 + r;
        betav[r] = (n < NU) ? beta[n] : 0.f;
    }
#pragma unroll
    for (int t8 = 0; t8 < 8; t8++) {
        float bc = bcU[16 * t8 + lr];
#pragma unroll
        for (int r = 0; r < 4; r++) {
            float v = fmaxf(acc[t8][r] + betav[r] * bc, 0.f);
            ys[(16 * w + lq * 4 + r) * 136 + 16 * t8 + lr] = (_Float16)v;
        }
    }
    __syncthreads();
    // GEMM2: K=128, 4 mfma steps
    f32x4 acc2[8];
#pragma unroll
    for (int t8 = 0; t8 < 8; t8++) acc2[t8] = zero;
    const half8* fW = (const half8*)fragW2;
#pragma unroll
    for (int s = 0; s < 4; s++) {
        half8 a2 = *(half8*)&ys[(16 * w + lr) * 136 + s * 32 + lq * 8];
#pragma unroll
        for (int t8 = 0; t8 < 8; t8++) {
            half8 bf = fW[(t8 * 4 + s) * 64 + l];
            acc2[t8] = __builtin_amdgcn_mfma_f32_16x16x32_f16(a2, bf, acc2[t8], 0, 0, 0);
        }
    }
#pragma unroll
    for (int r = 0; r < 4; r++) {
        int n = n0 + 16 * w + lq * 4 + r;
        if (n < NU) {
            float s = dinv[n];
#pragma unroll
            for (int t8 = 0; t8 < 8; t8++) {
                int c = 16 * t8 + lr;
                h2p[n * 128 + c] = (_Float16)((acc2[t8][r] + b2[c]) * s);
            }
        }
    }
}

// ============ fused movie chain (MFMA): (x_movie @ WcM + bcM) -> relu -> @W2 + b2
//              -> relu -> project with We_m -> P   (padded stride PSTR)
__global__ void __launch_bounds__(256) k_movie(
        const float* __restrict__ xm,
        const _Float16* __restrict__ fragWcM, const float* __restrict__ bcM,
        const _Float16* __restrict__ fragW2, const float* __restrict__ b2,
        const float* __restrict__ We, float* __restrict__ P) {
    __shared__ _Float16 xs[64 * 72];   // 64 rows x K=64 (pad 72)
    __shared__ _Float16 ys[64 * 136];
    int t = threadIdx.x;
    int n0 = blockIdx.x * 64;
    {   // stage x_movie -> xs fp16
        int r = t >> 2, c0 = (t & 3) * 16;
        int n = n0 + r;
        float4 a = make_float4(0.f, 0.f, 0.f, 0.f), b = a, c = a, d = a;
        if (n < NM) {
            const float4* g4 = (const float4*)xm;
            a = g4[n * 16 + (c0 >> 2)];
            b = g4[n * 16 + (c0 >> 2) + 1];
            c = g4[n * 16 + (c0 >> 2) + 2];
            d = g4[n * 16 + (c0 >> 2) + 3];
        }
        half8 h0, h1;
        h0[0] = (_Float16)a.x; h0[1] = (_Float16)a.y; h0[2] = (_Float16)a.z; h0[3] = (_Float16)a.w;
        h0[4] = (_Float16)b.x; h0[5] = (_Float16)b.y; h0[6] = (_Float16)b.z; h0[7] = (_Float16)b.w;
        h1[0] = (_Float16)c.x; h1[1] = (_Float16)c.y; h1[2] = (_Float16)c.z; h1[3] = (_Float16)c.w;
        h1[4] = (_Float16)d.x; h1[5] = (_Float16)d.y; h1[6] = (_Float16)d.z; h1[7] = (_Float16)d.w;
        *(half8*)&xs[r * 72 + c0] = h0;
        *(half8*)&xs[r * 72 + c0 + 8] = h1;
    }
    __syncthreads();
    int l = t & 63, w = t >> 6;
    int lr = l & 15, lq = l >> 4;
    const half8* fM = (const half8*)fragWcM;
    f32x4 zero = {0.f, 0.f, 0.f, 0.f};
    f32x4 acc[8];
#pragma unroll
    for (int t8 = 0; t8 < 8; t8++) acc[t8] = zero;
#pragma unroll
    for (int s = 0; s < 2; s++) {
        half8 af = *(half8*)&xs[(16 * w + lr) * 72 + s * 32 + lq * 8];
#pragma unroll
        for (int t8 = 0; t8 < 8; t8++) {
            half8 bf = fM[(t8 * 2 + s) * 64 + l];
            acc[t8] = __builtin_amdgcn_mfma_f32_16x16x32_f16(af, bf, acc[t8], 0, 0, 0);
        }
    }
#pragma unroll
    for (int t8 = 0; t8 < 8; t8++) {
        float bc = bcM[16 * t8 + lr];
#pragma unroll
        for (int r = 0; r < 4; r++) {
            float v = fmaxf(acc[t8][r] + bc, 0.f);
            ys[(16 * w + lq * 4 + r) * 136 + 16 * t8 + lr] = (_Float16)v;
        }
    }
    __syncthreads();
    f32x4 acc2[8];
#pragma unroll
    for (int t8 = 0; t8 < 8; t8++) acc2[t8] = zero;
    const half8* fW = (const half8*)fragW2;
#pragma unroll
    for (int s = 0; s < 4; s++) {
        half8 a2 = *(half8*)&ys[(16 * w + lr) * 136 + s * 32 + lq * 8];
#pragma unroll
        for (int t8 = 0; t8 < 8; t8++) {
            half8 bf = fW[(t8 * 4 + s) * 64 + l];
            acc2[t8] = __builtin_amdgcn_mfma_f32_16x16x32_f16(a2, bf, acc2[t8], 0, 0, 0);
        }
    }
    // fused epilogue: relu(acc2 + b2), project with We movie half (fp32), write P.
    float v[8][4];
#pragma unroll
    for (int t8 = 0; t8 < 8; t8++) {
        float bv = b2[16 * t8 + lr];
#pragma unroll
        for (int r = 0; r < 4; r++) v[t8][r] = fmaxf(acc2[t8][r] + bv, 0.f);
    }
#pragma unroll
    for (int q = 0; q < NC; q++) {
        float pq[4] = {0.f, 0.f, 0.f, 0.f};
#pragma unroll
        for (int t8 = 0; t8 < 8; t8++) {
            float wv = We[q * 256 + 128 + 16 * t8 + lr];
#pragma unroll
            for (int r = 0; r < 4; r++) pq[r] += wv * v[t8][r];
        }
#pragma unroll
        for (int r = 0; r < 4; r++) {
            float sv = pq[r];
            sv += __shfl_xor(sv, 1, 64);
            sv += __shfl_xor(sv, 2, 64);
            sv += __shfl_xor(sv, 4, 64);
            sv += __shfl_xor(sv, 8, 64);
            int n = n0 + 16 * w + lq * 4 + r;
            if (lr == 0 && n < NM) P[(size_t)(NU + n) * PSTR + q] = sv;
        }
    }
}

// ============ layer-2 aggregation + fused projection -> P_u (with be) ============
// slot list = csr + self at slot deg + zero-row padding (row NU of h2p is zeros).
// One unrolled round of 32 slots = 8 independent 256B gathers in flight (99.6% of nodes);
// packed-fp16 tree sum (values |h2p| ~ 0.02, error negligible), single convert.
__global__ void k_agg2(const _Float16* __restrict__ hv, const int* __restrict__ offsets,
                       const unsigned short* __restrict__ csr, const float* __restrict__ dinv,
                       const float* __restrict__ We, const float* __restrict__ be,
                       float* __restrict__ P) {
    int t = threadIdx.x;
    int l = t & 63, w = t >> 6;
    int n = blockIdx.x * 4 + w;
    int g = l >> 4, i = l & 15;   // 4 row-groups x 16 lanes (8 fp16 features each)
    int s = offsets[n], e = offsets[n + 1];
    int deg = e - s;
    int dtot = deg + 1;   // + self slot
    int idx = (l < deg) ? (int)csr[s + l] : (l == deg ? n : NU);
    const half8* hv8 = (const half8*)hv;   // row r at hv8[r*16 + i]
    float acc[8];
    {   // round 0: slots 0..31 -> 8 loads in flight per lane
        int r0 = __shfl(idx, g, 64),      r1 = __shfl(idx, 4 + g, 64);
        int r2 = __shfl(idx, 8 + g, 64),  r3 = __shfl(idx, 12 + g, 64);
        int r4 = __shfl(idx, 16 + g, 64), r5 = __shfl(idx, 20 + g, 64);
        int r6 = __shfl(idx, 24 + g, 64), r7 = __shfl(idx, 28 + g, 64);
        half8 a0 = hv8[r0 * 16 + i], a1 = hv8[r1 * 16 + i];
        half8 a2 = hv8[r2 * 16 + i], a3 = hv8[r3 * 16 + i];
        half8 a4 = hv8[r4 * 16 + i], a5 = hv8[r5 * 16 + i];
        half8 a6 = hv8[r6 * 16 + i], a7 = hv8[r7 * 16 + i];
        half8 q = ((a0 + a1) + (a2 + a3)) + ((a4 + a5) + (a6 + a7));
#pragma unroll
        for (int k = 0; k < 8; k++) acc[k] = (float)q[k];
    }
    if (__builtin_expect(dtot > 32, 0)) {   // ~0.4% of nodes
        int r0 = __shfl(idx, 32 + g, 64), r1 = __shfl(idx, 36 + g, 64);
        int r2 = __shfl(idx, 40 + g, 64), r3 = __shfl(idx, 44 + g, 64);
        int r4 = __shfl(idx, 48 + g, 64), r5 = __shfl(idx, 52 + g, 64);
        int r6 = __shfl(idx, 56 + g, 64), r7 = __shfl(idx, 60 + g, 64);
        half8 a0 = hv8[r0 * 16 + i], a1 = hv8[r1 * 16 + i];
        half8 a2 = hv8[r2 * 16 + i], a3 = hv8[r3 * 16 + i];
        half8 a4 = hv8[r4 * 16 + i], a5 = hv8[r5 * 16 + i];
        half8 a6 = hv8[r6 * 16 + i], a7 = hv8[r7 * 16 + i];
        half8 q = ((a0 + a1) + (a2 + a3)) + ((a4 + a5) + (a6 + a7));
#pragma unroll
        for (int k = 0; k < 8; k++) acc[k] += (float)q[k];
        if (__builtin_expect(dtot > 64, 0)) {   // essentially never
            for (int jj = 64 + g; jj < dtot; jj += 4) {
                int rr = (jj < deg) ? (int)csr[s + jj] : n;
                half8 aa = hv8[rr * 16 + i];
#pragma unroll
                for (int k = 0; k < 8; k++) acc[k] += (float)aa[k];
            }
        }
    }
#pragma unroll
    for (int k = 0; k < 8; k++) {
        acc[k] += __shfl_xor(acc[k], 16, 64);
        acc[k] += __shfl_xor(acc[k], 32, 64);
    }
    float dn = dinv[n];
    float v[8];
#pragma unroll
    for (int k = 0; k < 8; k++) v[k] = fmaxf(acc[k] * dn, 0.f);
    // projection: each 16-lane group handles q = g, g+4, g+8 (NC=10)
    for (int q = g; q < NC; q += 4) {
        const float4* wq = (const float4*)&We[q * 256 + i * 8];
        float4 w0 = wq[0], w1 = wq[1];
        float p = w0.x * v[0] + w0.y * v[1] + w0.z * v[2] + w0.w * v[3]
                + w1.x * v[4] + w1.y * v[5] + w1.z * v[6] + w1.w * v[7];
        p += __shfl_xor(p, 1, 64);
        p += __shfl_xor(p, 2, 64);
        p += __shfl_xor(p, 4, 64);
        p += __shfl_xor(p, 8, 64);
        if (i == 0) P[n * PSTR + q] = p + be[q];
    }
}

// ============ edge output: out[e] = P[row[e]] + P[NU + col[e]] (PSTR-padded rows) ============
__global__ void k_edge_out(const int* __restrict__ row, const int* __restrict__ col,
                           const float* __restrict__ P, float* __restrict__ out, int E) {
    __shared__ float ls[256 * 11];
    int t = threadIdx.x;
    int e0 = blockIdx.x * 256;
    int e = e0 + t;
    if (e < E) {
        int r = row[e], c = col[e];
        const f32x4* pu = (const f32x4*)(P + (size_t)r * PSTR);
        const f32x4* pm = (const f32x4*)(P + (size_t)(NU + c) * PSTR);
        f32x4 u0 = pu[0], u1 = pu[1], u2 = pu[2];
        f32x4 m0 = pm[0], m1 = pm[1], m2 = pm[2];
        u0 += m0; u1 += m1; u2 += m2;
        float* d = &ls[t * 11];
        d[0] = u0[0]; d[1] = u0[1]; d[2] = u0[2]; d[3] = u0[3];
        d[4] = u1[0]; d[5] = u1[1]; d[6] = u1[2]; d[7] = u1[3];
        d[8] = u2[0]; d[9] = u2[1];
    }
    __syncthreads();
    int nvals = (E - e0 < 256 ? E - e0 : 256) * NC;
    size_t base = (size_t)e0 * NC;
    for (int k = t; k < nvals; k += 256) {
        int ee = k / NC, q = k - ee * NC;
        out[base + k] = ls[ee * 11 + q];
    }
}

extern "C" void kernel_launch(void* const* d_in, const int* in_sizes, int n_in,
                              void* d_out, int out_size, void* d_ws, size_t ws_size,
                              hipStream_t stream) {
    const float* x_user  = (const float*)d_in[0];
    const float* x_movie = (const float*)d_in[1];
    const int*   ei      = (const int*)d_in[2];
    const float* Wu = (const float*)d_in[3];
    const float* bu = (const float*)d_in[4];
    const float* Wm = (const float*)d_in[5];
    const float* bm = (const float*)d_in[6];
    const float* W1 = (const float*)d_in[7];
    const float* b1 = (const float*)d_in[8];
    const float* W2 = (const float*)d_in[9];
    const float* b2 = (const float*)d_in[10];
    const float* We = (const float*)d_in[11];
    const float* be = (const float*)d_in[12];
    float* out = (float*)d_out;

    int E = in_sizes[2] / 2;
    const int* row = ei;
    const int* col = ei + E;

    char* p = (char*)d_ws;
    auto alloc = [&](size_t bytes) -> void* {
        void* r = (void*)p;
        p += (bytes + 255) & ~(size_t)255;
        return r;
    };
    int*            counts     = (int*)alloc((size_t)NU * 4);
    int*            offsets    = (int*)alloc((size_t)(NU + 1) * 4);
    unsigned short* csr16      = (unsigned short*)alloc((size_t)E * 2);
    unsigned int*   pairs      = (unsigned int*)alloc((size_t)NB * CAP * 4);
    int*            bucket_cur = (int*)alloc((size_t)NB * 4);
    float*          dinv       = (float*)alloc((size_t)(NU + 1) * 4);
    float*          beta       = (float*)alloc((size_t)NU * 4);
    int*            sums       = (int*)alloc((size_t)256 * 4);
    float*          WcUT       = (float*)alloc((size_t)FU * HD * 4);
    float*          WcMT       = (float*)alloc((size_t)FM * HD * 4);
    float*          W2T        = (float*)alloc((size_t)HD * HD * 4);
    float*          bcU        = (float*)alloc((size_t)HD * 4);
    float*          bcM        = (float*)alloc((size_t)HD * 4);
    _Float16*       fragWcU    = (_Float16*)alloc((size_t)4096 * 2);
    _Float16*       fragWcM    = (_Float16*)alloc((size_t)8192 * 2);
    _Float16*       fragW2     = (_Float16*)alloc((size_t)16384 * 2);
    __half2*        xs16       = (__half2*)alloc((size_t)(NU + 1) * FU * 2);
    float*          gfull      = (float*)alloc((size_t)NU * FU * 4);
    _Float16*       h2p        = (_Float16*)alloc((size_t)(NU + 1) * HD * 2);
    float*          P          = (float*)alloc((size_t)NN * PSTR * 4);

    const int tb = 256;
    const int nscan = (NU + 255) / 256;  // 196

    hipMemsetAsync(bucket_cur, 0, (size_t)NB * 4, stream);
    k_bucket<<<(E + CHUNK - 1) / CHUNK, 256, 0, stream>>>(row, col, E, bucket_cur, pairs);
    k_bcount<<<NB, 256, 0, stream>>>(pairs, bucket_cur, counts);
    k_scanA<<<nscan, 256, 0, stream>>>(counts, sums);
    k_scanB<<<1, 256, 0, stream>>>(sums, nscan, offsets, dinv,
                                   (float4*)(xs16 + (size_t)NU * 16),
                                   (float4*)(h2p + (size_t)NU * HD));
    k_scanC<<<nscan, 256, 0, stream>>>(counts, sums, offsets, dinv);
    k_scatter<<<NB, 256, 0, stream>>>(pairs, bucket_cur, offsets, csr16);

    k_fold<<<113, 256, 0, stream>>>(Wu, bu, Wm, bm, W1, b1, W2, WcUT, bcU, WcMT, bcM, W2T);
    k_wfrag<<<14, 256, 0, stream>>>(WcUT, WcMT, W2T, fragWcU, fragWcM, fragW2);
    k_half<<<(NU * FU / 2 + 255) / 256, 256, 0, stream>>>(x_user, dinv, xs16, NU * FU / 2);

    k_agg1<<<NU / 4, 256, 0, stream>>>((const _Float16*)xs16, offsets, csr16, dinv,
                                       gfull, beta);

    k_user<<<(NU + 63) / 64, 256, 0, stream>>>(gfull, beta, fragWcU, bcU, fragW2, b2, dinv, h2p);
    k_movie<<<(NM + 63) / 64, 256, 0, stream>>>(x_movie, fragWcM, bcM, fragW2, b2, We, P);

    k_agg2<<<NU / 4, 256, 0, stream>>>((const _Float16*)h2p, offsets, csr16, dinv, We, be, P);

    k_edge_out<<<(E + tb - 1) / tb, tb, 0, stream>>>(row, col, P, out, E);
}